// Round 3
// baseline (482.190 us; speedup 1.0000x reference)
//
#include <hip/hip_runtime.h>

// Integrate-and-fire, TBN layout. One thread per 4 consecutive neurons.
// History:
//  R4 (177us, 431MB, VGPR=32): bitmask epilogue removed store-ack
//      serialization; latency-bound at 2.4 TB/s.
//  R5 (213us, 667MB): 2 cols + PF8 ring @ (256,4): BW 3.1 TB/s but grid=1024
//      halved occupancy and dual store streams bloated WRITE 1.62x.
//  R6 (188us, 509MB): C-level PF8 ring @ (256,8): compiler COLLAPSED the
//      ring (VGPR stayed 32 -- can't hold 8 v4f in 32 regs). BW 2.7 TB/s.
//  R7: force the ring with inline asm. Volatile global_load_dwordx4 pins
//      issue order; counted s_waitcnt vmcnt(7) (never 0 until drain) keeps
//      8 x 1KiB loads in flight per wave. Tying each wait to its slot via
//      "+v" makes the consumer data-dependent on the wait (no hoisting).
//      R4 skeleton otherwise: 1 col/thread, grid 2048 = 8 blocks/CU,
//      loads are the ONLY vmem ops in the main loop, single nt-store
//      stream epilogue (minimal WRITE_SIZE per R4/R5 A-B).

typedef float v4f __attribute__((ext_vector_type(4)));

#define T_STEPS 32
#define PF 8

__global__ __launch_bounds__(256, 8) void if_kernel(const v4f* __restrict__ x,
                                                    v4f* __restrict__ y,
                                                    int bn4) {
    int idx = blockIdx.x * blockDim.x + threadIdx.x;
    if (idx >= bn4) return;

    const v4f* xp = x + idx;

    float v0 = 0.f, v1 = 0.f, v2 = 0.f, v3 = 0.f;
    unsigned m0 = 0u, m1 = 0u, m2 = 0u, m3 = 0u;

    // ---- Prologue: issue PF loads (8 x 1 KiB per wave in flight) ----
    v4f r[PF];
#pragma unroll
    for (int j = 0; j < PF; ++j) {
        const v4f* p = xp + (size_t)j * bn4;
        asm volatile("global_load_dwordx4 %0, %1, off"
                     : "=v"(r[j])
                     : "v"(p));
    }

    // Each step: wait until THIS slot's load retired (vmcnt(N_) newer
    // remain in flight), consume, refill the slot. All indices are
    // compile-time constants -> r[] stays in registers (rule #20).
#define IF_STEP(T_, N_)                                                      \
    {                                                                        \
        asm volatile("s_waitcnt vmcnt(" #N_ ")"                              \
                     : "+v"(r[(T_) & (PF - 1)]));                            \
        v4f xv = r[(T_) & (PF - 1)];                                         \
        if ((T_) + PF < T_STEPS) {                                           \
            const v4f* p = xp + (size_t)((T_) + PF) * bn4;                   \
            asm volatile("global_load_dwordx4 %0, %1, off"                   \
                         : "=v"(r[(T_) & (PF - 1)])                          \
                         : "v"(p));                                          \
        }                                                                    \
        float a0 = v0 + xv.x;                                                \
        float a1 = v1 + xv.y;                                                \
        float a2 = v2 + xv.z;                                                \
        float a3 = v3 + xv.w;                                                \
        bool s0 = a0 >= 1.0f;                                                \
        bool s1 = a1 >= 1.0f;                                                \
        bool s2 = a2 >= 1.0f;                                                \
        bool s3 = a3 >= 1.0f;                                                \
        m0 |= (unsigned)s0 << (T_);                                          \
        m1 |= (unsigned)s1 << (T_);                                          \
        m2 |= (unsigned)s2 << (T_);                                          \
        m3 |= (unsigned)s3 << (T_);                                          \
        v0 = s0 ? a0 - 1.0f : a0;                                            \
        v1 = s1 ? a1 - 1.0f : a1;                                            \
        v2 = s2 ? a2 - 1.0f : a2;                                            \
        v3 = s3 ? a3 - 1.0f : a3;                                            \
    }

    // Steady state: vmcnt(7). Drain tail: 6,5,...,0 (issued-minus-retired
    // shrinks once refills stop at t=23).
    IF_STEP(0, 7)  IF_STEP(1, 7)  IF_STEP(2, 7)  IF_STEP(3, 7)
    IF_STEP(4, 7)  IF_STEP(5, 7)  IF_STEP(6, 7)  IF_STEP(7, 7)
    IF_STEP(8, 7)  IF_STEP(9, 7)  IF_STEP(10, 7) IF_STEP(11, 7)
    IF_STEP(12, 7) IF_STEP(13, 7) IF_STEP(14, 7) IF_STEP(15, 7)
    IF_STEP(16, 7) IF_STEP(17, 7) IF_STEP(18, 7) IF_STEP(19, 7)
    IF_STEP(20, 7) IF_STEP(21, 7) IF_STEP(22, 7) IF_STEP(23, 7)
    IF_STEP(24, 7) IF_STEP(25, 6) IF_STEP(26, 5) IF_STEP(27, 4)
    IF_STEP(28, 3) IF_STEP(29, 2) IF_STEP(30, 1) IF_STEP(31, 0)
#undef IF_STEP

    // ---- Epilogue: expand bitmasks, single sequential nt-store stream ----
    // Stores feed nothing -> no waitcnt in this loop. Single stream per
    // thread keeps WRITE_SIZE at ~1.05x ideal (R4 vs R5 evidence).
    v4f* yp = y + idx;
#pragma unroll
    for (int t = 0; t < T_STEPS; ++t) {
        v4f out;
        out.x = ((m0 >> t) & 1u) ? 1.0f : 0.0f;
        out.y = ((m1 >> t) & 1u) ? 1.0f : 0.0f;
        out.z = ((m2 >> t) & 1u) ? 1.0f : 0.0f;
        out.w = ((m3 >> t) & 1u) ? 1.0f : 0.0f;
        __builtin_nontemporal_store(out, yp + (size_t)t * bn4);
    }
}

extern "C" void kernel_launch(void* const* d_in, const int* in_sizes, int n_in,
                              void* d_out, int out_size, void* d_ws, size_t ws_size,
                              hipStream_t stream) {
    const float* x = (const float*)d_in[0];
    float* y = (float*)d_out;

    int total = in_sizes[0];        // T*B*N = 67,108,864
    int bn = total / T_STEPS;       // B*N  =  2,097,152
    int bn4 = bn / 4;               //        524,288 float4 columns

    int block = 256;
    int grid = (bn4 + block - 1) / block;  // 2048 blocks = 8 per CU

    if_kernel<<<grid, block, 0, stream>>>((const v4f*)x, (v4f*)y, bn4);
}